// Round 1
// baseline (1300.839 us; speedup 1.0000x reference)
//
#include <hip/hip_runtime.h>
#include <math.h>

// Problem constants (B=16, H=W=56, C=512, window=7)
#define NTOK_PER_B 3136
#define NBATCH 16
#define M_TOK (NTOK_PER_B * NBATCH)   // 50176
#define CDIM 512
#define NWIN 448                      // 3136 / 7
#define SCALE 0.04419417382415922f    // 512^-0.5

// ---------------------------------------------------------------------------
// Kernel 1: out[M,512] = x[M,512] @ w[512,512] + bias[512]
// 128x128 tile, BK=16, 256 threads, 8x8 per thread, fp32 vector FMA.
// grid = (M/128, 512/128)
// ---------------------------------------------------------------------------
__global__ __launch_bounds__(256) void qkv_gemm_f32(
    const float* __restrict__ A,
    const float* __restrict__ W,
    const float* __restrict__ bias,
    float* __restrict__ out)
{
    __shared__ float As[16][128];   // [k][m] (transposed for fragment reads)
    __shared__ float Bs[16][128];   // [k][n]

    const int t  = threadIdx.x;
    const int tx = t & 15;          // 0..15 -> 8 cols (4 + 4)
    const int ty = t >> 4;          // 0..15 -> 8 rows (4 + 4)
    const int bm = blockIdx.x;
    const int bn = blockIdx.y;
    const int row0 = bm * 128;
    const int col0 = bn * 128;

    // A-tile load mapping: thread -> rows (t>>2) and (t>>2)+64, k-quad (t&3)*4
    const int ar = t >> 2;            // 0..63
    const int ak = (t & 3) << 2;      // 0,4,8,12
    // B-tile load mapping: k rows t>>5 and (t>>5)+8, n-quad (t&31)*4
    const int kb = t >> 5;            // 0..7
    const int nb = (t & 31) << 2;     // 0..124

    const float* Aptr = A + (size_t)(row0 + ar) * CDIM + ak;
    const float* Wptr = W + (size_t)kb * CDIM + col0 + nb;

    float acc[8][8];
    #pragma unroll
    for (int r = 0; r < 8; ++r)
        #pragma unroll
        for (int c = 0; c < 8; ++c) acc[r][c] = 0.f;

    for (int k0 = 0; k0 < CDIM; k0 += 16) {
        // prefetch into registers
        float4 a0 = *(const float4*)(Aptr + k0);
        float4 a1 = *(const float4*)(Aptr + k0 + 64 * CDIM);
        float4 b0 = *(const float4*)(Wptr + (size_t)k0 * CDIM);
        float4 b1 = *(const float4*)(Wptr + (size_t)(k0 + 8) * CDIM);

        __syncthreads();   // previous iteration's LDS reads done
        As[ak + 0][ar]      = a0.x;
        As[ak + 1][ar]      = a0.y;
        As[ak + 2][ar]      = a0.z;
        As[ak + 3][ar]      = a0.w;
        As[ak + 0][ar + 64] = a1.x;
        As[ak + 1][ar + 64] = a1.y;
        As[ak + 2][ar + 64] = a1.z;
        As[ak + 3][ar + 64] = a1.w;
        *(float4*)&Bs[kb][nb]     = b0;
        *(float4*)&Bs[kb + 8][nb] = b1;
        __syncthreads();

        #pragma unroll
        for (int k = 0; k < 16; ++k) {
            float4 av0 = *(const float4*)&As[k][ty * 4];
            float4 av1 = *(const float4*)&As[k][64 + ty * 4];
            float4 bv0 = *(const float4*)&Bs[k][tx * 4];
            float4 bv1 = *(const float4*)&Bs[k][64 + tx * 4];
            float a8[8] = {av0.x, av0.y, av0.z, av0.w, av1.x, av1.y, av1.z, av1.w};
            float b8[8] = {bv0.x, bv0.y, bv0.z, bv0.w, bv1.x, bv1.y, bv1.z, bv1.w};
            #pragma unroll
            for (int r = 0; r < 8; ++r)
                #pragma unroll
                for (int c = 0; c < 8; ++c)
                    acc[r][c] = fmaf(a8[r], b8[c], acc[r][c]);
        }
    }

    // epilogue: bias + store
    float bsv[8];
    #pragma unroll
    for (int c = 0; c < 4; ++c) {
        bsv[c]     = bias[col0 + tx * 4 + c];
        bsv[c + 4] = bias[col0 + 64 + tx * 4 + c];
    }
    #pragma unroll
    for (int r = 0; r < 8; ++r) {
        int row = row0 + ((r < 4) ? (ty * 4 + r) : (64 + ty * 4 + (r - 4)));
        float4 o0 = make_float4(acc[r][0] + bsv[0], acc[r][1] + bsv[1],
                                acc[r][2] + bsv[2], acc[r][3] + bsv[3]);
        float4 o1 = make_float4(acc[r][4] + bsv[4], acc[r][5] + bsv[5],
                                acc[r][6] + bsv[6], acc[r][7] + bsv[7]);
        *(float4*)(out + (size_t)row * CDIM + col0 + tx * 4)      = o0;
        *(float4*)(out + (size_t)row * CDIM + col0 + 64 + tx * 4) = o1;
    }
}

// ---------------------------------------------------------------------------
// Kernel 2: local attention, one block per (batch, window).
// 7 queries attend to 14 keys (previous window + current window).
// k is L2-normalized (folded into the score), self-token score = -5e4,
// causal (t_q < t_k) and pad (window 0, j<7) masked with -FLT_MAX.
// 256 threads: thread t owns channels t and t+256.
// ---------------------------------------------------------------------------
__global__ __launch_bounds__(256) void local_attn_f32(
    const float* __restrict__ q,
    const float* __restrict__ k,
    const float* __restrict__ v,
    float* __restrict__ out)
{
    const int blk   = blockIdx.x;
    const int batch = blk / NWIN;
    const int win   = blk % NWIN;
    const int t     = threadIdx.x;
    const int lane  = t & 63;
    const int wid   = t >> 6;

    const long long qbase = ((long long)batch * NTOK_PER_B + (long long)win * 7) * CDIM;
    const long long kbase = qbase - 7LL * CDIM;   // token (win-1)*7; valid only if win>0 for j<7

    __shared__ float partial[4][112];  // [wave][98 dots + 14 norms]
    __shared__ float scores[98];
    __shared__ float norms[14];
    __shared__ float attnw[98];

    const int c0 = t;
    const int c1 = t + 256;

    // ---- load K rows into registers ----
    float kreg[14][2];
    #pragma unroll
    for (int j = 0; j < 14; ++j) {
        const bool valid = (win > 0) || (j >= 7);
        kreg[j][0] = valid ? k[kbase + (long long)j * CDIM + c0] : 0.f;
        kreg[j][1] = valid ? k[kbase + (long long)j * CDIM + c1] : 0.f;
    }

    // ---- norm partials ----
    {
        float np[14];
        #pragma unroll
        for (int j = 0; j < 14; ++j)
            np[j] = kreg[j][0] * kreg[j][0] + kreg[j][1] * kreg[j][1];
        #pragma unroll
        for (int j = 0; j < 14; ++j) {
            float s = np[j];
            #pragma unroll
            for (int o = 32; o >= 1; o >>= 1) s += __shfl_xor(s, o, 64);
            np[j] = s;
        }
        if (lane == 0) {
            #pragma unroll
            for (int j = 0; j < 14; ++j) partial[wid][98 + j] = np[j];
        }
    }

    // ---- per-row dot partials ----
    #pragma unroll
    for (int i = 0; i < 7; ++i) {
        const float q0 = q[qbase + (long long)i * CDIM + c0];
        const float q1 = q[qbase + (long long)i * CDIM + c1];
        float dp[14];
        #pragma unroll
        for (int j = 0; j < 14; ++j)
            dp[j] = fmaf(q0, kreg[j][0], q1 * kreg[j][1]);
        #pragma unroll
        for (int j = 0; j < 14; ++j) {
            float s = dp[j];
            #pragma unroll
            for (int o = 32; o >= 1; o >>= 1) s += __shfl_xor(s, o, 64);
            dp[j] = s;
        }
        if (lane == 0) {
            #pragma unroll
            for (int j = 0; j < 14; ++j) partial[wid][i * 14 + j] = dp[j];
        }
    }
    __syncthreads();

    // ---- combine waves ----
    if (t < 112) {
        float s = partial[0][t] + partial[1][t] + partial[2][t] + partial[3][t];
        if (t < 98) scores[t] = s;
        else        norms[t - 98] = sqrtf(s);
    }
    __syncthreads();

    // ---- mask + softmax (7 threads, one per query row) ----
    if (t < 7) {
        const int i = t;
        float sc[14];
        #pragma unroll
        for (int j = 0; j < 14; ++j) {
            if (j > i + 7 || (win == 0 && j < 7)) {
                sc[j] = -3.402823466e38f;              // causal / pad
            } else if (j == i + 7) {
                sc[j] = -5e4f;                         // shared-qk self token
            } else {
                sc[j] = scores[i * 14 + j] / fmaxf(norms[j], 1e-12f) * SCALE;
            }
        }
        float m = sc[0];
        #pragma unroll
        for (int j = 1; j < 14; ++j) m = fmaxf(m, sc[j]);
        float sum = 0.f;
        #pragma unroll
        for (int j = 0; j < 14; ++j) {
            float e = expf(sc[j] - m);
            sc[j] = e;
            sum += e;
        }
        const float inv = 1.f / sum;
        #pragma unroll
        for (int j = 0; j < 14; ++j) attnw[i * 14 + j] = sc[j] * inv;
    }
    __syncthreads();

    // ---- PV: out[i][c] = sum_j attn[i][j] * v[j][c] ----
    float o0[7], o1[7];
    #pragma unroll
    for (int i = 0; i < 7; ++i) { o0[i] = 0.f; o1[i] = 0.f; }
    #pragma unroll
    for (int j = 0; j < 14; ++j) {
        const bool valid = (win > 0) || (j >= 7);
        const float v0 = valid ? v[kbase + (long long)j * CDIM + c0] : 0.f;
        const float v1 = valid ? v[kbase + (long long)j * CDIM + c1] : 0.f;
        #pragma unroll
        for (int i = 0; i < 7; ++i) {
            const float a = attnw[i * 14 + j];
            o0[i] = fmaf(a, v0, o0[i]);
            o1[i] = fmaf(a, v1, o1[i]);
        }
    }
    #pragma unroll
    for (int i = 0; i < 7; ++i) {
        out[qbase + (long long)i * CDIM + c0] = o0[i];
        out[qbase + (long long)i * CDIM + c1] = o1[i];
    }
}

// ---------------------------------------------------------------------------
extern "C" void kernel_launch(void* const* d_in, const int* in_sizes, int n_in,
                              void* d_out, int out_size, void* d_ws, size_t ws_size,
                              hipStream_t stream)
{
    const float* x  = (const float*)d_in[0];
    const float* wq = (const float*)d_in[1];
    const float* bq = (const float*)d_in[2];
    const float* wk = (const float*)d_in[3];
    const float* bk = (const float*)d_in[4];
    const float* wv = (const float*)d_in[5];
    const float* bv = (const float*)d_in[6];
    float* out = (float*)d_out;

    float* q = (float*)d_ws;                       // 50176*512 f32
    float* k = q + (size_t)M_TOK * CDIM;
    float* v = k + (size_t)M_TOK * CDIM;

    dim3 gg(M_TOK / 128, CDIM / 128);
    dim3 gb(256);
    qkv_gemm_f32<<<gg, gb, 0, stream>>>(x, wq, bq, q);
    qkv_gemm_f32<<<gg, gb, 0, stream>>>(x, wk, bk, k);
    qkv_gemm_f32<<<gg, gb, 0, stream>>>(x, wv, bv, v);

    local_attn_f32<<<NBATCH * NWIN, 256, 0, stream>>>(q, k, v, out);
}

// Round 2
// 405.147 us; speedup vs baseline: 3.2108x; 3.2108x over previous
//
#include <hip/hip_runtime.h>
#include <math.h>

// Problem constants (B=16, H=W=56, C=512, window=7)
#define NTOK_PER_B 3136
#define NBATCH 16
#define M_TOK (NTOK_PER_B * NBATCH)   // 50176
#define CDIM 512
#define NWIN 448                      // 3136 / 7
#define SCALE 0.04419417382415922f    // 512^-0.5

typedef _Float16 half8 __attribute__((ext_vector_type(8)));
typedef float f32x4 __attribute__((ext_vector_type(4)));

#define GLOAD16(g, l) __builtin_amdgcn_global_load_lds( \
    (const __attribute__((address_space(1))) void*)(g),  \
    (__attribute__((address_space(3))) void*)(l), 16, 0, 0)

__device__ __forceinline__ float wave_sum64(float s) {
    #pragma unroll
    for (int o = 32; o >= 1; o >>= 1) s += __shfl_xor(s, o, 64);
    return s;
}

// ---------------------------------------------------------------------------
// x (fp32) -> fp16, 8 elems/thread
// ---------------------------------------------------------------------------
__global__ __launch_bounds__(256) void cvt_f32_f16(
    const float* __restrict__ x, _Float16* __restrict__ y)
{
    const size_t i = ((size_t)blockIdx.x * 256 + threadIdx.x) * 8;
    const float4 a = *(const float4*)(x + i);
    const float4 b = *(const float4*)(x + i + 4);
    half8 o;
    o[0] = (_Float16)a.x; o[1] = (_Float16)a.y; o[2] = (_Float16)a.z; o[3] = (_Float16)a.w;
    o[4] = (_Float16)b.x; o[5] = (_Float16)b.y; o[6] = (_Float16)b.z; o[7] = (_Float16)b.w;
    *(half8*)(y + i) = o;
}

// ---------------------------------------------------------------------------
// W [K=512][N=512] fp32 -> Wt [N][K] fp16 (transposed), 3 matrices via z
// ---------------------------------------------------------------------------
__global__ __launch_bounds__(256) void cvt_w_t(
    const float* __restrict__ w0, const float* __restrict__ w1,
    const float* __restrict__ w2, _Float16* __restrict__ wt)
{
    const float* w = (blockIdx.z == 0) ? w0 : ((blockIdx.z == 1) ? w1 : w2);
    _Float16* o = wt + (size_t)blockIdx.z * CDIM * CDIM;
    __shared__ float tile[32][33];
    const int tx = threadIdx.x & 31;
    const int ty = threadIdx.x >> 5;          // 0..7
    const int k0 = blockIdx.x * 32;
    const int n0 = blockIdx.y * 32;
    #pragma unroll
    for (int r = 0; r < 32; r += 8)
        tile[ty + r][tx] = w[(size_t)(k0 + ty + r) * CDIM + n0 + tx];
    __syncthreads();
    #pragma unroll
    for (int r = 0; r < 32; r += 8)
        o[(size_t)(n0 + ty + r) * CDIM + k0 + tx] = (_Float16)tile[tx][ty + r];
}

// ---------------------------------------------------------------------------
// GEMM: out[z][M,512] = xh[M,512] @ Wt[z]^T + bias[z]   (fp16 in, fp32 acc,
// fp16 out). 128x128 tile, BK=32, 4 waves (2x2), 4x4 16x16x32 MFMA frags.
// grid = (392, 4, 3)
// ---------------------------------------------------------------------------
__global__ __launch_bounds__(256) void qkv_gemm_f16(
    const _Float16* __restrict__ A,
    const _Float16* __restrict__ Wt,
    const float* __restrict__ b0, const float* __restrict__ b1,
    const float* __restrict__ b2,
    _Float16* __restrict__ out)
{
    const int z = blockIdx.z;
    const _Float16* W = Wt + (size_t)z * CDIM * CDIM;
    const float* bias = (z == 0) ? b0 : ((z == 1) ? b1 : b2);
    _Float16* O = out + (size_t)z * (size_t)M_TOK * CDIM;

    __shared__ _Float16 As[128 * 32];   // row-major [row][k], 64B rows
    __shared__ _Float16 Bs[128 * 32];   // row-major [n][k]

    const int t    = threadIdx.x;
    const int lane = t & 63;
    const int wid  = t >> 6;
    const int wrow = (wid >> 1) * 64;
    const int wcol = (wid & 1) * 64;
    const int row0 = blockIdx.x * 128;
    const int col0 = blockIdx.y * 128;

    // staging: chunk c (0..511) -> LDS byte c*16, row c/4, k-slot (c%4)*8
    const _Float16* aSrc0 = A + (size_t)(row0 + (t >> 2)) * CDIM + (t & 3) * 8;
    const _Float16* aSrc1 = aSrc0 + (size_t)64 * CDIM;
    const _Float16* bSrc0 = W + (size_t)(col0 + (t >> 2)) * CDIM + (t & 3) * 8;
    const _Float16* bSrc1 = bSrc0 + (size_t)64 * CDIM;
    _Float16* aDst0 = As + t * 8;
    _Float16* aDst1 = As + (t + 256) * 8;
    _Float16* bDst0 = Bs + t * 8;
    _Float16* bDst1 = Bs + (t + 256) * 8;

    f32x4 acc[4][4];
    #pragma unroll
    for (int m = 0; m < 4; ++m)
        #pragma unroll
        for (int n = 0; n < 4; ++n)
            acc[m][n] = (f32x4){0.f, 0.f, 0.f, 0.f};

    const int fr  = lane & 15;
    const int q8o = (lane >> 4) * 8;

    for (int k0 = 0; k0 < CDIM; k0 += 32) {
        GLOAD16(aSrc0 + k0, aDst0);
        GLOAD16(aSrc1 + k0, aDst1);
        GLOAD16(bSrc0 + k0, bDst0);
        GLOAD16(bSrc1 + k0, bDst1);
        __syncthreads();   // drains vmcnt: LDS tile ready

        half8 af[4], bf[4];
        #pragma unroll
        for (int m = 0; m < 4; ++m)
            af[m] = *(const half8*)(As + (wrow + m * 16 + fr) * 32 + q8o);
        #pragma unroll
        for (int n = 0; n < 4; ++n)
            bf[n] = *(const half8*)(Bs + (wcol + n * 16 + fr) * 32 + q8o);
        #pragma unroll
        for (int m = 0; m < 4; ++m)
            #pragma unroll
            for (int n = 0; n < 4; ++n)
                acc[m][n] = __builtin_amdgcn_mfma_f32_16x16x32_f16(
                    af[m], bf[n], acc[m][n], 0, 0, 0);
        __syncthreads();   // LDS reads done before next overwrite
    }

    // epilogue: bias + fp16 store. C/D: col=lane&15, row=(lane>>4)*4+reg
    const int rq = (lane >> 4) * 4;
    float bval[4];
    #pragma unroll
    for (int n = 0; n < 4; ++n)
        bval[n] = bias[col0 + wcol + n * 16 + fr];
    #pragma unroll
    for (int m = 0; m < 4; ++m) {
        #pragma unroll
        for (int r = 0; r < 4; ++r) {
            const int row = row0 + wrow + m * 16 + rq + r;
            _Float16* op = O + (size_t)row * CDIM + col0 + wcol + fr;
            #pragma unroll
            for (int n = 0; n < 4; ++n)
                op[n * 16] = (_Float16)(acc[m][n][r] + bval[n]);
        }
    }
}

// ---------------------------------------------------------------------------
// k row L2-normalization in-place (fp16), one wave per token
// ---------------------------------------------------------------------------
__global__ __launch_bounds__(256) void knorm_f16(_Float16* __restrict__ k)
{
    const int tok  = blockIdx.x * 4 + (threadIdx.x >> 6);
    const int lane = threadIdx.x & 63;
    _Float16* p = k + (size_t)tok * CDIM + lane * 8;
    half8 v = *(const half8*)p;
    float s = 0.f;
    #pragma unroll
    for (int e = 0; e < 8; ++e) {
        const float f = (float)v[e];
        s = fmaf(f, f, s);
    }
    s = wave_sum64(s);
    const float scale = 1.f / fmaxf(sqrtf(s), 1e-12f);
    #pragma unroll
    for (int e = 0; e < 8; ++e)
        v[e] = (_Float16)((float)v[e] * scale);
    *(half8*)p = v;
}

// ---------------------------------------------------------------------------
// Local attention: one block per (batch, window), 7 waves = 1 wave per query
// row. Lane owns 8 channels. k pre-normalized. self=-5e4, causal/pad=-FLT_MAX.
// ---------------------------------------------------------------------------
__global__ __launch_bounds__(448) void local_attn_f16(
    const _Float16* __restrict__ q,
    const _Float16* __restrict__ k,
    const _Float16* __restrict__ v,
    float* __restrict__ out)
{
    const int blk   = blockIdx.x;
    const int batch = blk / NWIN;
    const int win   = blk % NWIN;
    const int i     = threadIdx.x >> 6;    // query row 0..6
    const int lane  = threadIdx.x & 63;
    const int c     = lane * 8;

    const long long tok0 = (long long)batch * NTOK_PER_B + (long long)win * 7;

    const half8 q8 = *(const half8*)(q + (tok0 + i) * CDIM + c);

    float dots[14];
    #pragma unroll
    for (int j = 0; j < 14; ++j) {
        const bool valid = (win > 0) || (j >= 7);
        float d = 0.f;
        if (valid) {
            const half8 k8 = *(const half8*)(k + (tok0 - 7 + j) * CDIM + c);
            #pragma unroll
            for (int e = 0; e < 8; ++e)
                d = fmaf((float)q8[e], (float)k8[e], d);
        }
        dots[j] = wave_sum64(d);
    }

    // mask + softmax (in-register, redundant across lanes)
    float sc[14];
    #pragma unroll
    for (int j = 0; j < 14; ++j) {
        const bool valid = (win > 0) || (j >= 7);
        if (j > i + 7 || !valid)  sc[j] = -3.402823466e38f;  // causal / pad
        else if (j == i + 7)      sc[j] = -5e4f;              // shared-qk self
        else                      sc[j] = dots[j] * SCALE;
    }
    float m = sc[0];
    #pragma unroll
    for (int j = 1; j < 14; ++j) m = fmaxf(m, sc[j]);
    float sum = 0.f;
    #pragma unroll
    for (int j = 0; j < 14; ++j) {
        sc[j] = __expf(sc[j] - m);
        sum += sc[j];
    }
    const float inv = 1.f / sum;

    // PV
    float o[8];
    #pragma unroll
    for (int e = 0; e < 8; ++e) o[e] = 0.f;
    #pragma unroll
    for (int j = 0; j < 14; ++j) {
        const bool valid = (win > 0) || (j >= 7);
        if (valid) {
            const half8 v8 = *(const half8*)(v + (tok0 - 7 + j) * CDIM + c);
            const float a = sc[j] * inv;
            #pragma unroll
            for (int e = 0; e < 8; ++e)
                o[e] = fmaf(a, (float)v8[e], o[e]);
        }
    }

    float* op = out + (tok0 + i) * CDIM + c;
    *(float4*)(op)     = make_float4(o[0], o[1], o[2], o[3]);
    *(float4*)(op + 4) = make_float4(o[4], o[5], o[6], o[7]);
}

// ---------------------------------------------------------------------------
extern "C" void kernel_launch(void* const* d_in, const int* in_sizes, int n_in,
                              void* d_out, int out_size, void* d_ws, size_t ws_size,
                              hipStream_t stream)
{
    const float* x  = (const float*)d_in[0];
    const float* wq = (const float*)d_in[1];
    const float* bq = (const float*)d_in[2];
    const float* wk = (const float*)d_in[3];
    const float* bk = (const float*)d_in[4];
    const float* wv = (const float*)d_in[5];
    const float* bv = (const float*)d_in[6];
    float* out = (float*)d_out;

    char* ws = (char*)d_ws;
    const size_t XH_BYTES = (size_t)M_TOK * CDIM * sizeof(_Float16);   // 51.4 MB
    const size_t WT_BYTES = (size_t)3 * CDIM * CDIM * sizeof(_Float16);
    _Float16* xh  = (_Float16*)ws;
    _Float16* wt  = (_Float16*)(ws + XH_BYTES);
    _Float16* qkv = (_Float16*)(ws + XH_BYTES + WT_BYTES);
    _Float16* qh = qkv;
    _Float16* kh = qkv + (size_t)M_TOK * CDIM;
    _Float16* vh = kh  + (size_t)M_TOK * CDIM;

    cvt_f32_f16<<<12544, 256, 0, stream>>>(x, xh);
    cvt_w_t<<<dim3(16, 16, 3), 256, 0, stream>>>(wq, wk, wv, wt);
    qkv_gemm_f16<<<dim3(M_TOK / 128, CDIM / 128, 3), 256, 0, stream>>>(
        xh, wt, bq, bk, bv, qkv);
    knorm_f16<<<M_TOK / 4, 256, 0, stream>>>(kh);
    local_attn_f16<<<NBATCH * NWIN, 448, 0, stream>>>(qh, kh, vh, out);
}